// Round 1
// baseline (188.099 us; speedup 1.0000x reference)
//
#include <hip/hip_runtime.h>
#include <math.h>

// DualClassify: dual (lane-level + trajectory-level) cross-entropy loss.
// B=256, L=16, K=64, T=50 in the reference data, but segment structure is
// read generically from the start/end index arrays.

#define LANE_WEIGHT 1.0f
#define TEMP_INV    10.0f   // 1 / 0.1

// ---------------------------------------------------------------------------
// Kernel 1: one block per lane (NL blocks x 256 threads).
//  Phase A: ADE per trajectory. Quad (4 threads) per traj; each quad streams
//           the traj's 25 float4s so one quad-step consumes one full 64B line.
//  Phase B: wave 0 does softmax(scores/TEMP) and log_softmax(traj_scores)
//           over the K trajs via 64-lane shuffles; writes ce_per_lane to ws.
// ---------------------------------------------------------------------------
__global__ __launch_bounds__(256) void lane_ce_kernel(
    const float* __restrict__ pred_candidates,  // [NT, T, 2]
    const float* __restrict__ pred_gt,          // [B, T, 2]
    const float* __restrict__ traj_scores,      // [NT, 1]
    const float* __restrict__ scales,           // [B]
    const int*   __restrict__ cls_se,           // [B, 2]
    const int*   __restrict__ trajs_se,         // [NL, 2]
    float*       __restrict__ ws_ce,            // [NL] output: ce per lane
    int B, int T)
{
    const int lane = blockIdx.x;
    const int tid  = threadIdx.x;

    __shared__ int    s_sample;
    __shared__ float4 s_gt4[64];   // T/2 <= 64 float4s (T=50 -> 25)
    __shared__ float  s_acc[64];   // per-traj ADE sums

    if (tid == 0) {
        // binary search: largest s with cls_start[s] <= lane
        int lo = 0, hi = B - 1;
        while (lo < hi) {
            int mid = (lo + hi + 1) >> 1;
            if (cls_se[2 * mid] <= lane) lo = mid; else hi = mid - 1;
        }
        s_sample = lo;
    }
    __syncthreads();
    const int sample = s_sample;
    const int t0 = trajs_se[2 * lane];
    const int t1 = trajs_se[2 * lane + 1];
    const int Kl = t1 - t0;        // trajs in this lane (64 in the data)

    // stage GT track for this sample into LDS
    float* s_gt = (float*)s_gt4;
    for (int i = tid; i < T * 2; i += blockDim.x)
        s_gt[i] = pred_gt[(size_t)sample * (T * 2) + i];
    __syncthreads();

    // ---- Phase A: ADE, quad-per-trajectory ----
    const int tl = tid >> 2;       // traj-local index 0..63
    const int q  = tid & 3;        // quad lane
    float partial = 0.0f;
    if (tl < Kl) {
        const float4* base =
            (const float4*)(pred_candidates + (size_t)(t0 + tl) * (T * 2));
        const int nf4 = T / 2;     // 25 float4s per traj (T*2 floats)
        for (int r = q; r < nf4; r += 4) {
            float4 c = base[r];
            float4 g = s_gt4[r];
            float dx0 = c.x - g.x, dy0 = c.y - g.y;
            float dx1 = c.z - g.z, dy1 = c.w - g.w;
            partial += sqrtf(dx0 * dx0 + dy0 * dy0 + 1e-12f)
                     + sqrtf(dx1 * dx1 + dy1 * dy1 + 1e-12f);
        }
    }
    // quad reduce (lanes tid^1, tid^2 are in the same wave)
    partial += __shfl_xor(partial, 1);
    partial += __shfl_xor(partial, 2);
    if (q == 0 && tl < Kl) s_acc[tl] = partial;
    __syncthreads();

    // ---- Phase B: dual softmax over K trajs (wave 0 only) ----
    if (tid < 64) {
        const int  j     = tid;
        const bool valid = (j < Kl);
        const float inv_scale = 1.0f / scales[sample];

        // scores/TEMP ; score = -(ade)/scale ; ade = acc/T
        float sc = valid ? (-(s_acc[j] / (float)T) * inv_scale * TEMP_INV)
                         : -INFINITY;
        float m = sc;
        for (int off = 32; off; off >>= 1) m = fmaxf(m, __shfl_xor(m, off));
        float e = valid ? expf(sc - m) : 0.0f;
        float Z = e;
        for (int off = 32; off; off >>= 1) Z += __shfl_xor(Z, off);
        float target = e / Z;

        float tsc = valid ? traj_scores[t0 + j] : -INFINITY;
        float m2 = tsc;
        for (int off = 32; off; off >>= 1) m2 = fmaxf(m2, __shfl_xor(m2, off));
        float e2 = valid ? expf(tsc - m2) : 0.0f;
        float Z2 = e2;
        for (int off = 32; off; off >>= 1) Z2 += __shfl_xor(Z2, off);
        float logp = (tsc - m2) - logf(Z2);

        float ce = valid ? (-target * logp) : 0.0f;
        for (int off = 32; off; off >>= 1) ce += __shfl_xor(ce, off);
        if (j == 0) ws_ce[lane] = ce;
    }
}

// ---------------------------------------------------------------------------
// Kernel 2: one block, thread s = sample s. Lane-level CE (softmax over the
// sample's lanes), oracle-weighted traj CE average, block reduce -> scalar.
// ---------------------------------------------------------------------------
__global__ __launch_bounds__(256) void sample_loss_kernel(
    const float* __restrict__ lane_scores,  // [NL]
    const int*   __restrict__ cls_oracle,   // [NL] (bool as int)
    const int*   __restrict__ cls_se,       // [B, 2]
    const float* __restrict__ ws_ce,        // [NL]
    float*       __restrict__ out,          // [1]
    int B)
{
    const int tid = threadIdx.x;
    float total = 0.0f;
    for (int s = tid; s < B; s += blockDim.x) {
        const int cs = cls_se[2 * s], ce_ = cls_se[2 * s + 1];
        float m = -INFINITY;
        for (int l = cs; l < ce_; ++l) m = fmaxf(m, lane_scores[l]);
        float Z = 0.0f; int cnt = 0;
        for (int l = cs; l < ce_; ++l) {
            Z += expf(lane_scores[l] - m);
            cnt += (cls_oracle[l] != 0);
        }
        const float lse = m + logf(Z);
        const float inv_cnt = 1.0f / (float)cnt;
        float lane_loss = 0.0f, traj_loss = 0.0f;
        for (int l = cs; l < ce_; ++l) {
            if (cls_oracle[l] != 0) {
                lane_loss += -(lane_scores[l] - lse);
                traj_loss += ws_ce[l];
            }
        }
        total += lane_loss * inv_cnt * LANE_WEIGHT + traj_loss * inv_cnt;
    }
    __shared__ float s_red[256];
    s_red[tid] = total;
    __syncthreads();
    for (int off = 128; off; off >>= 1) {
        if (tid < off) s_red[tid] += s_red[tid + off];
        __syncthreads();
    }
    if (tid == 0) out[0] = s_red[0] / (float)B;
}

// ---------------------------------------------------------------------------
extern "C" void kernel_launch(void* const* d_in, const int* in_sizes, int n_in,
                              void* d_out, int out_size, void* d_ws, size_t ws_size,
                              hipStream_t stream)
{
    const float* lane_scores     = (const float*)d_in[0];
    const float* traj_scores     = (const float*)d_in[1];
    const float* pred_candidates = (const float*)d_in[2];
    const float* pred_gt         = (const float*)d_in[3];
    const float* scales          = (const float*)d_in[4];
    const int*   cls_oracle      = (const int*)d_in[5];
    const int*   cls_se          = (const int*)d_in[6];
    const int*   trajs_se        = (const int*)d_in[7];

    const int NL = in_sizes[0];
    const int NT = in_sizes[1];
    const int B  = in_sizes[6] / 2;
    const int T  = in_sizes[2] / (NT * 2);   // 50

    float* ws_ce = (float*)d_ws;             // NL floats of scratch
    float* out   = (float*)d_out;

    lane_ce_kernel<<<NL, 256, 0, stream>>>(
        pred_candidates, pred_gt, traj_scores, scales,
        cls_se, trajs_se, ws_ce, B, T);

    sample_loss_kernel<<<1, 256, 0, stream>>>(
        lane_scores, cls_oracle, cls_se, ws_ce, out, B);
}